// Round 7
// baseline (8514.655 us; speedup 1.0000x reference)
//
#include <hip/hip_runtime.h>
#include <hip/hip_bf16.h>
#include <cstdint>
#include <cstddef>

// ---------------------------------------------------------------------------
// 2-layer GRU decoder. B=8192, H=512, ENC=1024, ATOM=64, 49 steps.
// R7: ONE fused kernel for the whole 49-step decode. The recurrence is
// per-row independent (state, argmax, embedding lookup are row-local; only
// weights are shared), so each of 256 blocks (512 thr, 8 waves, 2/SIMD)
// owns 32 rows and keeps h0/h1 in LDS (fp32) across all steps:
//   - no intermediate state traffic to HBM (~100 MB/step in the 3-kernel
//     version), no 147 launches, no per-kernel pipeline ramps.
//   - A-frags: ds_read from LDS state + f32->bf16 cvt (bit-identical to the
//     old h0b/h1b bf16 mirrors). B-frags: verified reg-loaded frag layout.
//   - ALL sync is __syncthreads() (5/step) - no manual vmcnt/barriers.
// LDS state layout: row stride 524 f32 (2096B = 131x16B, odd) + granule XOR
//   elem(row,c) at row*524 + ((c>>3)^(row&7))*8 + (c&7)
// -> wave A-reads spread over all 8 16B-slots (bank floor).
// Wave roles: wave w owns gate-triples T=w*4+tr (192 gate cols = 64 h cols);
// gru1 accumulates gh r,z INTO gi acc via MFMA C-in (n kept separate).
// Weight L2 streaming (4.6MB/CU/step ~ 34us) is the new model ceiling.
// Frag layout for a [R][512] bf16 matrix (prep-time transform, verified):
//   elem(r,k) -> ((r>>4)*16+(k>>5))*512 + ((k>>3)&3)*128 + (r&15)*8 + (k&7)
// ---------------------------------------------------------------------------

typedef __attribute__((ext_vector_type(8))) __bf16 bf16x8;
typedef __attribute__((ext_vector_type(4))) __bf16 bf16x4;
typedef __attribute__((ext_vector_type(4))) float f32x4;

#define B_ROWS 8192
#define HID 512
#define GATE3 1536
#define ATOM 64
#define NSTEP 49
#define LROW 524   // padded LDS row stride in f32 (2096 B, odd multiple of 16B)

#define GLOAD_LDS16(gp, sp)                                                   \
  __builtin_amdgcn_global_load_lds(                                           \
      (__attribute__((address_space(1))) void*)(gp),                          \
      (__attribute__((address_space(3))) void*)(sp), 16, 0, 0)

__device__ inline float sig_(float x) { return 1.f / (1.f + __expf(-x)); }
__device__ inline float tanh_(float x) { return 2.f / (1.f + __expf(-2.f * x)) - 1.f; }

// LDS offset (in floats) of state elem (row, c), swizzled
__device__ __forceinline__ int lof(int row, int c) {
    return row * LROW + (((c >> 3) ^ (row & 7)) << 3) + (c & 7);
}

// Build MFMA A-frag for (row, kt) from fp32 LDS state: lane q gives cols
// kt*32 + q*8 .. +8 (one 8-f32 granule), converted to bf16 (RNE, identical
// to the old bf16 state mirrors).
__device__ __forceinline__ bf16x8 ldsA(const float* hs, int row, int kt, int q) {
    const int g = ((kt << 2) + q) ^ (row & 7);
    const float* p0 = &hs[row * LROW + (g << 3)];
    const float4 a = *(const float4*)p0;
    const float4 b = *(const float4*)(p0 + 4);
    bf16x8 r;
    r[0] = (__bf16)a.x; r[1] = (__bf16)a.y; r[2] = (__bf16)a.z; r[3] = (__bf16)a.w;
    r[4] = (__bf16)b.x; r[5] = (__bf16)b.y; r[6] = (__bf16)b.z; r[7] = (__bf16)b.w;
    return r;
}

// ---------------------------------------------------------------------------
// The fused decode kernel. 256 blocks x 512 threads; block owns rows
// m0..m0+32; 8 waves, wave w owns gate-triples w*4..w*4+3 (h cols w*64..+64).
// ---------------------------------------------------------------------------
__global__ __launch_bounds__(512, 2) void decode_fused(
    const float* __restrict__ h0f_g, const float* __restrict__ h1f_g,
    const __bf16* __restrict__ whh0f, const float* __restrict__ G0p,
    const float* __restrict__ bhh0p,
    const __bf16* __restrict__ wih1f, const __bf16* __restrict__ whh1f,
    const float* __restrict__ bih1p, const float* __restrict__ bhh1p,
    const __bf16* __restrict__ woutf, const float* __restrict__ bout,
    float* __restrict__ y)
{
    __shared__ float h0s[32 * LROW];   // 65.5 KB
    __shared__ float h1s[32 * LROW];   // 65.5 KB
    __shared__ int   p_s[32];

    const int tid = threadIdx.x, lane = tid & 63, w = tid >> 6;
    const int u = lane & 15, q = lane >> 4;
    const int m0 = blockIdx.x * 32;

    // ---- one-time: load init state (fp32) into swizzled LDS ----
    for (int idx = tid; idx < 32 * 128; idx += 512) {
        const int row = idx >> 7, c0 = (idx & 127) << 2;   // c0 multiple of 4
        const int off = row * LROW + (((c0 >> 3) ^ (row & 7)) << 3) + (c0 & 7);
        *(float4*)&h0s[off] = *(const float4*)&h0f_g[(size_t)(m0 + row) * HID + c0];
        *(float4*)&h1s[off] = *(const float4*)&h1f_g[(size_t)(m0 + row) * HID + c0];
    }
    if (tid < 32) p_s[tid] = 1;   // SOS

    // ---- per-wave constants (hoisted across all 49 steps) ----
    const size_t wbase = (size_t)(w * 192) * HID + (size_t)lane * 8;
    const __bf16* B0 = whh0f + wbase;
    const __bf16* Bi = wih1f + wbase;
    const __bf16* Bh = whh1f + wbase;
    const __bf16* Bw = woutf + (size_t)lane * 8;

    float bh0r[4], bh0z[4], bh0n[4];           // gru0 hidden biases
    float b1r[4], b1z[4], b1in[4], b1hn[4];    // gru1 (r,z input+hidden folded)
    #pragma unroll
    for (int tr = 0; tr < 4; ++tr) {
        const int qb = (w * 4 + tr) * 48 + u;
        bh0r[tr] = bhh0p[qb]; bh0z[tr] = bhh0p[qb + 16]; bh0n[tr] = bhh0p[qb + 32];
        b1r[tr]  = bih1p[qb] + bhh1p[qb];
        b1z[tr]  = bih1p[qb + 16] + bhh1p[qb + 16];
        b1in[tr] = bih1p[qb + 32];
        b1hn[tr] = bhh1p[qb + 32];
    }
    float bo[4] = {0.f, 0.f, 0.f, 0.f};
    if (w < 2) {
        #pragma unroll
        for (int nf = 0; nf < 4; ++nf) bo[nf] = bout[nf * 16 + u];
    }
    __syncthreads();

    for (int step = 0; step < NSTEP; ++step) {
        // ================= gru0: gh0 = h0 @ whh0^T; gates; h0 <- new =======
        {
            f32x4 acc0[2][4][3] = {};
            #pragma unroll 4
            for (int kt = 0; kt < 16; ++kt) {
                const bf16x8 a0 = ldsA(h0s, u, kt, q);
                const bf16x8 a1 = ldsA(h0s, u + 16, kt, q);
                #pragma unroll
                for (int tr = 0; tr < 4; ++tr)
                    #pragma unroll
                    for (int g = 0; g < 3; ++g) {
                        const bf16x8 bf = *(const bf16x8*)(B0 + (size_t)(tr * 48 + g * 16 + kt) * HID);
                        acc0[0][tr][g] = __builtin_amdgcn_mfma_f32_16x16x32_bf16(a0, bf, acc0[0][tr][g], 0, 0, 0);
                        acc0[1][tr][g] = __builtin_amdgcn_mfma_f32_16x16x32_bf16(a1, bf, acc0[1][tr][g], 0, 0, 0);
                    }
            }
            __syncthreads();   // all waves done READING h0s

            int pv[2][4];
            #pragma unroll
            for (int mf = 0; mf < 2; ++mf)
                #pragma unroll
                for (int r = 0; r < 4; ++r) pv[mf][r] = p_s[mf * 16 + q * 4 + r];

            #pragma unroll
            for (int mf = 0; mf < 2; ++mf)
                #pragma unroll
                for (int tr = 0; tr < 4; ++tr) {
                    const int j  = (w * 4 + tr) * 16 + u;
                    const int qb = (w * 4 + tr) * 48 + u;
                    #pragma unroll
                    for (int r = 0; r < 4; ++r) {
                        const int row = mf * 16 + q * 4 + r;
                        const float* g0 = G0p + (size_t)pv[mf][r] * GATE3 + qb;
                        const float rr = sig_(g0[0]  + acc0[mf][tr][0][r] + bh0r[tr]);
                        const float zz = sig_(g0[16] + acc0[mf][tr][1][r] + bh0z[tr]);
                        const float nn = tanh_(g0[32] + rr * (acc0[mf][tr][2][r] + bh0n[tr]));
                        const int o = lof(row, j);
                        h0s[o] = (1.f - zz) * nn + zz * h0s[o];
                    }
                }
        }
        __syncthreads();   // new h0 visible to all

        // ================= gru1: gi = h0new @ wih1^T; gh = h1 @ whh1^T =====
        {
            f32x4 ai[2][4][3] = {};
            #pragma unroll 4
            for (int kt = 0; kt < 16; ++kt) {
                const bf16x8 a0 = ldsA(h0s, u, kt, q);
                const bf16x8 a1 = ldsA(h0s, u + 16, kt, q);
                #pragma unroll
                for (int tr = 0; tr < 4; ++tr)
                    #pragma unroll
                    for (int g = 0; g < 3; ++g) {
                        const bf16x8 bf = *(const bf16x8*)(Bi + (size_t)(tr * 48 + g * 16 + kt) * HID);
                        ai[0][tr][g] = __builtin_amdgcn_mfma_f32_16x16x32_bf16(a0, bf, ai[0][tr][g], 0, 0, 0);
                        ai[1][tr][g] = __builtin_amdgcn_mfma_f32_16x16x32_bf16(a1, bf, ai[1][tr][g], 0, 0, 0);
                    }
            }
            f32x4 an[2][4] = {};
            #pragma unroll 4
            for (int kt = 0; kt < 16; ++kt) {
                const bf16x8 a0 = ldsA(h1s, u, kt, q);
                const bf16x8 a1 = ldsA(h1s, u + 16, kt, q);
                #pragma unroll
                for (int tr = 0; tr < 4; ++tr) {
                    const bf16x8 br = *(const bf16x8*)(Bh + (size_t)(tr * 48 + 0 * 16 + kt) * HID);
                    ai[0][tr][0] = __builtin_amdgcn_mfma_f32_16x16x32_bf16(a0, br, ai[0][tr][0], 0, 0, 0);
                    ai[1][tr][0] = __builtin_amdgcn_mfma_f32_16x16x32_bf16(a1, br, ai[1][tr][0], 0, 0, 0);
                    const bf16x8 bz = *(const bf16x8*)(Bh + (size_t)(tr * 48 + 1 * 16 + kt) * HID);
                    ai[0][tr][1] = __builtin_amdgcn_mfma_f32_16x16x32_bf16(a0, bz, ai[0][tr][1], 0, 0, 0);
                    ai[1][tr][1] = __builtin_amdgcn_mfma_f32_16x16x32_bf16(a1, bz, ai[1][tr][1], 0, 0, 0);
                    const bf16x8 bn = *(const bf16x8*)(Bh + (size_t)(tr * 48 + 2 * 16 + kt) * HID);
                    an[0][tr] = __builtin_amdgcn_mfma_f32_16x16x32_bf16(a0, bn, an[0][tr], 0, 0, 0);
                    an[1][tr] = __builtin_amdgcn_mfma_f32_16x16x32_bf16(a1, bn, an[1][tr], 0, 0, 0);
                }
            }
            __syncthreads();   // all waves done READING h0s/h1s

            #pragma unroll
            for (int mf = 0; mf < 2; ++mf)
                #pragma unroll
                for (int tr = 0; tr < 4; ++tr) {
                    const int j = (w * 4 + tr) * 16 + u;
                    #pragma unroll
                    for (int r = 0; r < 4; ++r) {
                        const int row = mf * 16 + q * 4 + r;
                        const float rr = sig_(ai[mf][tr][0][r] + b1r[tr]);
                        const float zz = sig_(ai[mf][tr][1][r] + b1z[tr]);
                        const float nn = tanh_(ai[mf][tr][2][r] + b1in[tr] +
                                               rr * (an[mf][tr][r] + b1hn[tr]));
                        const int o = lof(row, j);
                        h1s[o] = (1.f - zz) * nn + zz * h1s[o];
                    }
                }
        }
        __syncthreads();   // new h1 visible

        // ================= out: logits, log_softmax, argmax ================
        if (w < 2) {
            f32x4 aq[4] = {};
            #pragma unroll 4
            for (int kt = 0; kt < 16; ++kt) {
                const bf16x8 af = ldsA(h1s, w * 16 + u, kt, q);
                #pragma unroll
                for (int nf = 0; nf < 4; ++nf) {
                    const bf16x8 bf = *(const bf16x8*)(Bw + (size_t)(nf * 16 + kt) * HID);
                    aq[nf] = __builtin_amdgcn_mfma_f32_16x16x32_bf16(af, bf, aq[nf], 0, 0, 0);
                }
            }
            float* ystep = y + (size_t)step * B_ROWS * ATOM;
            #pragma unroll
            for (int r = 0; r < 4; ++r) {
                const int lr = w * 16 + q * 4 + r;
                float l[4];
                #pragma unroll
                for (int nf = 0; nf < 4; ++nf) l[nf] = aq[nf][r] + bo[nf];

                float mv = l[0]; int mi = u;
                #pragma unroll
                for (int nf = 1; nf < 4; ++nf)
                    if (l[nf] > mv) { mv = l[nf]; mi = nf * 16 + u; }
                #pragma unroll
                for (int off = 1; off <= 8; off <<= 1) {
                    const float ov = __shfl_xor(mv, off, 64);
                    const int   oi = __shfl_xor(mi, off, 64);
                    if (ov > mv || (ov == mv && oi < mi)) { mv = ov; mi = oi; }
                }
                float se = 0.f;
                #pragma unroll
                for (int nf = 0; nf < 4; ++nf) se += __expf(l[nf] - mv);
                #pragma unroll
                for (int off = 1; off <= 8; off <<= 1) se += __shfl_xor(se, off, 64);
                const float lse = logf(se);

                float* yrow = ystep + (size_t)(m0 + lr) * ATOM;
                #pragma unroll
                for (int nf = 0; nf < 4; ++nf)
                    yrow[nf * 16 + u] = l[nf] - mv - lse;
                if (u == 0) p_s[lr] = mi;
            }
        }
        __syncthreads();   // p_s ready; h1s reads done
    }
}

// ---------------------------------------------------------------------------
// Init GEMM (enc -> h): 128x128 tile, LDS-staged, tanh epilogue split h0|h1.
// Runs once; unchanged.
// ---------------------------------------------------------------------------
__global__ __launch_bounds__(256) void gemm_init(
    const __bf16* __restrict__ A, const __bf16* __restrict__ B,
    int N, int K, const float* __restrict__ bias,
    float* __restrict__ H0f, __bf16* __restrict__ H0b,
    float* __restrict__ H1f, __bf16* __restrict__ H1b)
{
    __shared__ __bf16 As[128 * 32];
    __shared__ __bf16 Bs[128 * 32];

    const int tid  = threadIdx.x;
    const int lane = tid & 63;
    const int w    = tid >> 6;
    const int wm   = w >> 1, wn = w & 1;
    const int m0   = blockIdx.x * 128;
    const int n0   = blockIdx.y * 128;

    f32x4 acc[4][4] = {};

    const int i0 = w * 64 + lane;
    const int i1 = i0 + 256;
    const __bf16* Ap0 = A + (size_t)(m0 + (i0 >> 2)) * K + (i0 & 3) * 8;
    const __bf16* Ap1 = A + (size_t)(m0 + (i1 >> 2)) * K + (i1 & 3) * 8;
    const __bf16* Bp0 = B + (size_t)(n0 + (i0 >> 2)) * K + (i0 & 3) * 8;
    const __bf16* Bp1 = B + (size_t)(n0 + (i1 >> 2)) * K + (i1 & 3) * 8;
    __bf16* As0 = As + w * 512;
    __bf16* As1 = As + 2048 + w * 512;
    __bf16* Bs0 = Bs + w * 512;
    __bf16* Bs1 = Bs + 2048 + w * 512;

    const int mrow = wm * 64 + (lane & 15);
    const int nrow = wn * 64 + (lane & 15);
    const int koff = (lane >> 4) * 8;

    for (int kt = 0; kt < K / 32; ++kt) {
        __syncthreads();
        GLOAD_LDS16(Ap0, As0);
        GLOAD_LDS16(Ap1, As1);
        GLOAD_LDS16(Bp0, Bs0);
        GLOAD_LDS16(Bp1, Bs1);
        Ap0 += 32; Ap1 += 32; Bp0 += 32; Bp1 += 32;
        __syncthreads();

        bf16x8 af[4], bfr[4];
        #pragma unroll
        for (int f = 0; f < 4; ++f) {
            af[f]  = *(const bf16x8*)&As[(mrow + f * 16) * 32 + koff];
            bfr[f] = *(const bf16x8*)&Bs[(nrow + f * 16) * 32 + koff];
        }
        #pragma unroll
        for (int mf = 0; mf < 4; ++mf)
            #pragma unroll
            for (int nf = 0; nf < 4; ++nf)
                acc[mf][nf] = __builtin_amdgcn_mfma_f32_16x16x32_bf16(
                    af[mf], bfr[nf], acc[mf][nf], 0, 0, 0);
    }

    const int colb = n0 + wn * 64 + (lane & 15);
    const int rowb = m0 + wm * 64 + ((lane >> 4) << 2);
    #pragma unroll
    for (int mf = 0; mf < 4; ++mf)
        #pragma unroll
        for (int nf = 0; nf < 4; ++nf) {
            const int col = colb + nf * 16;
            #pragma unroll
            for (int r = 0; r < 4; ++r) {
                const int row = rowb + mf * 16 + r;
                const float v = tanhf(acc[mf][nf][r] + bias[col]);
                if (col < HID) {
                    H0f[(size_t)row * HID + col] = v;
                    H0b[(size_t)row * HID + col] = (__bf16)v;
                } else {
                    H1f[(size_t)row * HID + col - HID] = v;
                    H1b[(size_t)row * HID + col - HID] = (__bf16)v;
                }
            }
        }
}

// ---------------------------------------------------------------------------
// prep kernels
// ---------------------------------------------------------------------------
__device__ inline int permQ(int q) {          // permuted q -> original row
    const int t = q / 48, rem = q % 48;
    return (rem / 16) * HID + t * 16 + (rem % 16);
}

// frag-layout offset for elem (r, k) of a [R][512] matrix
__device__ inline size_t fragOff(int r, int k) {
    return (size_t)((r >> 4) * 16 + (k >> 5)) * 512 +
           ((k >> 3) & 3) * 128 + (r & 15) * 8 + (k & 7);
}

__global__ __launch_bounds__(256) void f2b(const float* __restrict__ s,
                                           __bf16* __restrict__ d, int n)
{
    const int i = (blockIdx.x * 256 + threadIdx.x) * 4;
    if (i + 3 < n) {
        const float4 v = *(const float4*)(s + i);
        bf16x4 o = { (__bf16)v.x, (__bf16)v.y, (__bf16)v.z, (__bf16)v.w };
        *(bf16x4*)(d + i) = o;
    }
}

// gate-perm + frag layout for the three 1536x512 GRU weights
__global__ __launch_bounds__(256) void f2bpf(const float* __restrict__ s,
                                             __bf16* __restrict__ d)
{
    const int idx = blockIdx.x * 256 + threadIdx.x;   // 1536*128
    const int q = idx >> 7, k4 = (idx & 127) << 2;
    const int o = permQ(q);
    const float4 v = *(const float4*)(s + (size_t)o * HID + k4);
    bf16x4 ov = { (__bf16)v.x, (__bf16)v.y, (__bf16)v.z, (__bf16)v.w };
    *(bf16x4*)(d + fragOff(q, k4)) = ov;
}

// frag layout for wout (64 x 512)
__global__ __launch_bounds__(256) void f2bf(const float* __restrict__ s,
                                            __bf16* __restrict__ d)
{
    const int idx = blockIdx.x * 256 + threadIdx.x;   // 64*128
    if (idx >= ATOM * 128) return;
    const int r = idx >> 7, k4 = (idx & 127) << 2;
    const float4 v = *(const float4*)(s + (size_t)r * HID + k4);
    bf16x4 ov = { (__bf16)v.x, (__bf16)v.y, (__bf16)v.z, (__bf16)v.w };
    *(bf16x4*)(d + fragOff(r, k4)) = ov;
}

__global__ __launch_bounds__(256) void bperm(const float* __restrict__ s,
                                             float* __restrict__ d)
{
    const int q = blockIdx.x * 256 + threadIdx.x;
    if (q < GATE3) d[q] = s[permQ(q)];
}

__global__ __launch_bounds__(256) void g0pk(const float* __restrict__ emb,
                                            const float* __restrict__ wih0,
                                            const float* __restrict__ bih0,
                                            float* __restrict__ G0p)
{
    const int i = blockIdx.x * 256 + threadIdx.x;   // 64*1536
    if (i >= ATOM * GATE3) return;
    const int a = i / GATE3, q = i % GATE3;
    const int o = permQ(q);
    float s = bih0[o];
    for (int k = 0; k < 50; ++k) s += emb[a * 50 + k] * wih0[o * 50 + k];
    G0p[i] = s;
}

// ---------------------------------------------------------------------------
extern "C" void kernel_launch(void* const* d_in, const int* in_sizes, int n_in,
                              void* d_out, int out_size, void* d_ws, size_t ws_size,
                              hipStream_t stream)
{
    (void)in_sizes; (void)n_in; (void)out_size; (void)ws_size;
    const float* enc   = (const float*)d_in[0];
    const float* emb   = (const float*)d_in[1];
    const float* w_h0  = (const float*)d_in[2];
    const float* b_h0  = (const float*)d_in[3];
    const float* w_ih0 = (const float*)d_in[4];
    const float* w_hh0 = (const float*)d_in[5];
    const float* b_ih0 = (const float*)d_in[6];
    const float* b_hh0 = (const float*)d_in[7];
    const float* w_ih1 = (const float*)d_in[8];
    const float* w_hh1 = (const float*)d_in[9];
    const float* b_ih1 = (const float*)d_in[10];
    const float* b_hh1 = (const float*)d_in[11];
    const float* w_out = (const float*)d_in[12];
    const float* b_out = (const float*)d_in[13];
    float* out = (float*)d_out;

    char* ws = (char*)d_ws;
    size_t off = 0;
    auto alloc = [&](size_t bytes) -> void* {
        void* pp = ws + off;
        off = (off + bytes + 255) & ~(size_t)255;
        return pp;
    };
    __bf16* whh0f = (__bf16*)alloc((size_t)GATE3 * HID * 2);
    __bf16* wih1f = (__bf16*)alloc((size_t)GATE3 * HID * 2);
    __bf16* whh1f = (__bf16*)alloc((size_t)GATE3 * HID * 2);
    __bf16* woutf = (__bf16*)alloc((size_t)ATOM * HID * 2);
    float*  G0p   = (float*) alloc((size_t)ATOM * GATE3 * 4);
    float*  bhh0p = (float*) alloc(GATE3 * 4);
    float*  bih1p = (float*) alloc(GATE3 * 4);
    float*  bhh1p = (float*) alloc(GATE3 * 4);
    float*  h0f = (float*) alloc((size_t)B_ROWS * HID * 4);
    __bf16* h0b = (__bf16*)alloc((size_t)B_ROWS * HID * 2);
    float*  h1f = (float*) alloc((size_t)B_ROWS * HID * 4);
    __bf16* h1b = (__bf16*)alloc((size_t)B_ROWS * HID * 2);
    __bf16* enc_b = (__bf16*)alloc((size_t)B_ROWS * 1024 * 2);
    __bf16* wh0b  = (__bf16*)alloc((size_t)1024 * 1024 * 2);

    // ---- prep ----
    f2b  <<<8192, 256, 0, stream>>>(enc,  enc_b, B_ROWS * 1024);
    f2b  <<<1024, 256, 0, stream>>>(w_h0, wh0b,  1024 * 1024);
    f2bf <<<32,   256, 0, stream>>>(w_out, woutf);
    f2bpf<<<768,  256, 0, stream>>>(w_hh0, whh0f);
    f2bpf<<<768,  256, 0, stream>>>(w_ih1, wih1f);
    f2bpf<<<768,  256, 0, stream>>>(w_hh1, whh1f);
    bperm<<<6, 256, 0, stream>>>(b_hh0, bhh0p);
    bperm<<<6, 256, 0, stream>>>(b_ih1, bih1p);
    bperm<<<6, 256, 0, stream>>>(b_hh1, bhh1p);
    g0pk<<<384, 256, 0, stream>>>(emb, w_ih0, b_ih0, G0p);

    gemm_init<<<dim3(B_ROWS / 128, 1024 / 128), 256, 0, stream>>>(
        enc_b, wh0b, 1024, 1024, b_h0, h0f, h0b, h1f, h1b);

    // ---- the whole 49-step decode: ONE kernel ----
    decode_fused<<<256, 512, 0, stream>>>(
        h0f, h1f, whh0f, G0p, bhh0p,
        wih1f, whh1f, bih1p, bhh1p,
        woutf, b_out, out);
}

// Round 8
// 5448.316 us; speedup vs baseline: 1.5628x; 1.5628x over previous
//
#include <hip/hip_runtime.h>
#include <hip/hip_bf16.h>
#include <cstdint>
#include <cstddef>

// ---------------------------------------------------------------------------
// 2-layer GRU decoder. B=8192, H=512, ENC=1024, ATOM=64, 49 steps.
// 3 kernels/step: gru0_step, gru1_fused, out_mfma (R7 single-kernel fusion
// regressed: per-block whole-weight streaming thrashes the 4MB XCD L2 --
// 41MB/step HBM refetch + 3.8e8 LDS conflicts on fp32 state reads).
// Gate-permuted weights: q = 48*(j/16) + 16*g + (j%16) <-> orig row g*512+j.
// Grid dim3(64,8): m-tile fastest-varying => XCD L2 locality on weights.
// R8: M=128 tiles, 8 row-frags/wave (was 4): each 3KB of B-frags per iter
//     now feeds 24 MFMAs (2x arithmetic per weight byte; K-loops were
//     L2-BW-bound on weight streaming -- MfmaUtil 16%). K2 fits acc in
//     128 VGPR via r/z K-concat: r,z gates are sums sig(gi+gh+b), so one
//     K=1024 accumulation (h0 phase kt<16, h1 phase kt>=16); only n split.
//     Verified R6 skeleton kept: 3-buf A, counted vmcnt(5), fenced
//     barriers, prologue vmcnt(0) drain, XOR swizzle (conflicts = 0).
// Frag layout for a [R][512] bf16 matrix read as MFMA A/B operand:
//     elem(r,k) -> ((r>>4)*16 + (k>>5))*512 + ((k>>3)&3)*128 + (r&15)*8 + (k&7)
//     => frag (fr,kt) is a contiguous 1KB block, lane l reads l*16B.
// ---------------------------------------------------------------------------

typedef __attribute__((ext_vector_type(8))) __bf16 bf16x8;
typedef __attribute__((ext_vector_type(4))) __bf16 bf16x4;
typedef __attribute__((ext_vector_type(4))) float f32x4;

#define B_ROWS 8192
#define HID 512
#define GATE3 1536
#define ATOM 64
#define NSTEP 49

#define GLOAD_LDS16(gp, sp)                                                   \
  __builtin_amdgcn_global_load_lds(                                           \
      (__attribute__((address_space(1))) void*)(gp),                          \
      (__attribute__((address_space(3))) void*)(sp), 16, 0, 0)

#define PROLOGUE_FENCE()                                                      \
  do {                                                                        \
    __builtin_amdgcn_sched_barrier(0);                                        \
    asm volatile("" ::: "memory");                                            \
  } while (0)

#define BARRIER_FENCED()                                                      \
  do {                                                                        \
    __builtin_amdgcn_s_barrier();                                             \
    asm volatile("" ::: "memory");                                            \
    __builtin_amdgcn_sched_barrier(0);                                        \
  } while (0)

__device__ inline float sig_(float x) { return 1.f / (1.f + __expf(-x)); }
__device__ inline float tanh_(float x) { return 2.f / (1.f + __expf(-2.f * x)) - 1.f; }

// ---------------------------------------------------------------------------
// K1: GRU0. gh0 = h0 @ whh0f^T; gi0 = G0p[p[row]] (b_ih0 folded);
// gate update -> h0_new. M=128, 4 waves, 8 row-frags/wave.
// A: LDS 3-buf (24KB) + swizzle, 2 stage-rounds/iter. B: reg-frags.
// Per iter: 2 stages + 3 B-loads -> vmcnt(5); ONE fenced barrier.
// ---------------------------------------------------------------------------
__global__ __launch_bounds__(256) void gru0_step(
    const __bf16* __restrict__ h0b_c, const __bf16* __restrict__ whh0f,
    const float* __restrict__ G0p, const int* __restrict__ p,
    const float* __restrict__ bhh0p,
    const float* __restrict__ h0f_c, float* __restrict__ h0f_n,
    __bf16* __restrict__ h0b_n)
{
    __shared__ __bf16 As[3][128 * 32];   // 3 x 8 KB

    const int tid = threadIdx.x, lane = tid & 63, w = tid >> 6;
    const int u = lane & 15, q = lane >> 4;
    const int m0 = blockIdx.x * 128;
    const int t_ = blockIdx.y * 4 + w;
    const int j  = t_ * 16 + u;
    const int qb = t_ * 48 + u;
    const int k0   = (q ^ ((u >> 1) & 3)) * 8;              // A read col
    const int scol = ((tid & 3) ^ ((tid >> 3) & 3)) * 8;    // A stage col
    const int wo = w * 512;

    const __bf16* Ap0 = h0b_c + (size_t)(m0 + (tid >> 2)) * HID + scol;      // rows 0..63
    const __bf16* Ap1 = Ap0 + (size_t)64 * HID;                              // rows 64..127
    const __bf16* Bf = whh0f + (size_t)(t_ * 48) * 512 + lane * 8;
    #define BFR0(g, kt) (*(const bf16x8*)(Bf + (size_t)((g) * 16 + (kt)) * 512))

    f32x4 acc[8][3] = {};
    bf16x8 bfr[2][3];

    GLOAD_LDS16(Ap0, &As[0][wo]);
    GLOAD_LDS16(Ap1, &As[0][2048 + wo]);
    Ap0 += 32; Ap1 += 32;
    bfr[0][0] = BFR0(0, 0);
    bfr[0][1] = BFR0(1, 0);
    bfr[0][2] = BFR0(2, 0);
    PROLOGUE_FENCE();

    #pragma unroll
    for (int kt = 0; kt < 16; ++kt) {
        const int cur3 = kt % 3, nxt3 = (kt + 1) % 3;
        const int cur2 = kt & 1;
        if (kt < 15) {
            GLOAD_LDS16(Ap0, &As[nxt3][wo]);
            GLOAD_LDS16(Ap1, &As[nxt3][2048 + wo]);
            Ap0 += 32; Ap1 += 32;
            bfr[cur2 ^ 1][0] = BFR0(0, kt + 1);
            bfr[cur2 ^ 1][1] = BFR0(1, kt + 1);
            bfr[cur2 ^ 1][2] = BFR0(2, kt + 1);
            if (kt == 0) asm volatile("s_waitcnt vmcnt(0)" ::: "memory");
            else         asm volatile("s_waitcnt vmcnt(5)" ::: "memory");
        } else {
            asm volatile("s_waitcnt vmcnt(0)" ::: "memory");
        }
        BARRIER_FENCED();                                   // As[cur3] ready

        bf16x8 af[8];
        #pragma unroll
        for (int mf = 0; mf < 8; ++mf)
            af[mf] = *(const bf16x8*)&As[cur3][(mf * 16 + u) * 32 + k0];
        __builtin_amdgcn_s_setprio(1);
        #pragma unroll
        for (int mf = 0; mf < 8; ++mf)
            #pragma unroll
            for (int g = 0; g < 3; ++g)
                acc[mf][g] = __builtin_amdgcn_mfma_f32_16x16x32_bf16(
                    af[mf], bfr[cur2][g], acc[mf][g], 0, 0, 0);
        __builtin_amdgcn_s_setprio(0);
    }

    const float bhr = bhh0p[qb], bhz = bhh0p[qb + 16], bhn = bhh0p[qb + 32];
    const int rbase = m0 + (q << 2);
    #pragma unroll
    for (int mf = 0; mf < 8; ++mf)
        #pragma unroll
        for (int r = 0; r < 4; ++r) {
            const int row = rbase + mf * 16 + r;
            const float* g0 = G0p + (size_t)p[row] * GATE3 + qb;
            const float rr = sig_(g0[0]  + acc[mf][0][r] + bhr);
            const float zz = sig_(g0[16] + acc[mf][1][r] + bhz);
            const float nn = tanh_(g0[32] + rr * (acc[mf][2][r] + bhn));
            const float hp = h0f_c[(size_t)row * HID + j];
            const float hv = (1.f - zz) * nn + zz * hp;
            h0f_n[(size_t)row * HID + j] = hv;
            h0b_n[(size_t)row * HID + j] = (__bf16)hv;
        }
}

// ---------------------------------------------------------------------------
// K2: GRU1. ONE K=1024 loop: phase 0 (kt<16) A=h0_new, B=wih1; phase 1
// (kt>=16) A=h1, B=whh1. r,z gates accumulate across both phases (they sum);
// n kept split (ani/anh). M=128, 4 waves, 8 row-frags/wave; acc 128 VGPR.
// Per iter: 2 stages + 3 B-loads -> vmcnt(5); ONE fenced barrier.
// ---------------------------------------------------------------------------
__global__ __launch_bounds__(256) void gru1_fused(
    const __bf16* __restrict__ h0b_n, const __bf16* __restrict__ wih1f,
    const __bf16* __restrict__ h1b_c, const __bf16* __restrict__ whh1f,
    const float* __restrict__ bih1p, const float* __restrict__ bhh1p,
    const float* __restrict__ h1f_c, float* __restrict__ h1f_n,
    __bf16* __restrict__ h1b_n)
{
    __shared__ __bf16 As[3][128 * 32];   // 3 x 8 KB (h0-tiles then h1-tiles)

    const int tid = threadIdx.x, lane = tid & 63, w = tid >> 6;
    const int u = lane & 15, q = lane >> 4;
    const int m0 = blockIdx.x * 128;
    const int t_ = blockIdx.y * 4 + w;
    const int j  = t_ * 16 + u;
    const int qb = t_ * 48 + u;
    const int k0   = (q ^ ((u >> 1) & 3)) * 8;
    const int scol = ((tid & 3) ^ ((tid >> 3) & 3)) * 8;
    const int wo = w * 512;

    const __bf16* Ai0 = h0b_n + (size_t)(m0 + (tid >> 2)) * HID + scol;
    const __bf16* Ai1 = Ai0 + (size_t)64 * HID;
    const __bf16* Ah0 = h1b_c + (size_t)(m0 + (tid >> 2)) * HID + scol;
    const __bf16* Ah1 = Ah0 + (size_t)64 * HID;
    const __bf16* Bi = wih1f + (size_t)(t_ * 48) * 512 + lane * 8;
    const __bf16* Bh = whh1f + (size_t)(t_ * 48) * 512 + lane * 8;

    f32x4 arz[8][2] = {};   // r,z accumulated over K=1024 (both phases)
    f32x4 ani[8] = {};      // n input part  (phase 0)
    f32x4 anh[8] = {};      // n hidden part (phase 1)
    bf16x8 bfr[2][3];

    GLOAD_LDS16(Ai0, &As[0][wo]);
    GLOAD_LDS16(Ai1, &As[0][2048 + wo]);
    #pragma unroll
    for (int g = 0; g < 3; ++g)
        bfr[0][g] = *(const bf16x8*)(Bi + (size_t)(g * 16) * 512);
    PROLOGUE_FENCE();

    #pragma unroll
    for (int kt = 0; kt < 32; ++kt) {
        const int cur3 = kt % 3, nxt3 = (kt + 1) % 3;
        const int cur2 = kt & 1;
        if (kt < 31) {
            const int kn = kt + 1;
            const __bf16* a0 = (kn < 16 ? Ai0 : Ah0) + (size_t)(kn & 15) * 32;
            const __bf16* a1 = (kn < 16 ? Ai1 : Ah1) + (size_t)(kn & 15) * 32;
            GLOAD_LDS16(a0, &As[nxt3][wo]);
            GLOAD_LDS16(a1, &As[nxt3][2048 + wo]);
            const __bf16* bb = (kn < 16 ? Bi : Bh);
            #pragma unroll
            for (int g = 0; g < 3; ++g)
                bfr[cur2 ^ 1][g] = *(const bf16x8*)(bb + (size_t)(g * 16 + (kn & 15)) * 512);
            if (kt == 0) asm volatile("s_waitcnt vmcnt(0)" ::: "memory");
            else         asm volatile("s_waitcnt vmcnt(5)" ::: "memory");
        } else {
            asm volatile("s_waitcnt vmcnt(0)" ::: "memory");
        }
        BARRIER_FENCED();

        bf16x8 af[8];
        #pragma unroll
        for (int mf = 0; mf < 8; ++mf)
            af[mf] = *(const bf16x8*)&As[cur3][(mf * 16 + u) * 32 + k0];
        __builtin_amdgcn_s_setprio(1);
        #pragma unroll
        for (int mf = 0; mf < 8; ++mf) {
            arz[mf][0] = __builtin_amdgcn_mfma_f32_16x16x32_bf16(
                af[mf], bfr[cur2][0], arz[mf][0], 0, 0, 0);
            arz[mf][1] = __builtin_amdgcn_mfma_f32_16x16x32_bf16(
                af[mf], bfr[cur2][1], arz[mf][1], 0, 0, 0);
            if (kt < 16)
                ani[mf] = __builtin_amdgcn_mfma_f32_16x16x32_bf16(
                    af[mf], bfr[cur2][2], ani[mf], 0, 0, 0);
            else
                anh[mf] = __builtin_amdgcn_mfma_f32_16x16x32_bf16(
                    af[mf], bfr[cur2][2], anh[mf], 0, 0, 0);
        }
        __builtin_amdgcn_s_setprio(0);
    }

    const float b1r  = bih1p[qb] + bhh1p[qb];
    const float b1z  = bih1p[qb + 16] + bhh1p[qb + 16];
    const float b1in = bih1p[qb + 32];
    const float b1hn = bhh1p[qb + 32];
    const int rbase = m0 + (q << 2);
    #pragma unroll
    for (int mf = 0; mf < 8; ++mf)
        #pragma unroll
        for (int r = 0; r < 4; ++r) {
            const int row = rbase + mf * 16 + r;
            const float rr = sig_(arz[mf][0][r] + b1r);
            const float zz = sig_(arz[mf][1][r] + b1z);
            const float nn = tanh_(ani[mf][r] + b1in + rr * (anh[mf][r] + b1hn));
            const float hp = h1f_c[(size_t)row * HID + j];
            const float hv = (1.f - zz) * nn + zz * hp;
            h1f_n[(size_t)row * HID + j] = hv;
            h1b_n[(size_t)row * HID + j] = (__bf16)hv;
        }
}

// ---------------------------------------------------------------------------
// K3: logits = h1_new @ w_out^T + b_out (BM=32, N=64, K=512); log_softmax +
// argmax fused. 256 blocks x 128 threads. Unchanged from R6.
// ---------------------------------------------------------------------------
__global__ __launch_bounds__(128) void out_mfma(
    const __bf16* __restrict__ h1b, const __bf16* __restrict__ woutf,
    const float* __restrict__ bout, float* __restrict__ y, int* __restrict__ p)
{
    __shared__ __bf16 As[3][32 * 32];   // 3 x 2 KB

    const int tid  = threadIdx.x;
    const int lane = tid & 63;
    const int w    = tid >> 6;            // 0..1
    const int m0   = blockIdx.x * 32;
    const int u    = lane & 15, q = lane >> 4;
    const int k0   = (q ^ ((u >> 1) & 3)) * 8;
    const int scol = ((tid & 3) ^ ((tid >> 3) & 3)) * 8;
    const int wo   = w * 512;

    f32x4 acc[4] = {};
    bf16x8 bfr[2][4];

    const __bf16* Ap = h1b + (size_t)(m0 + (tid >> 2)) * HID + scol;
    const __bf16* Bf = woutf + lane * 8;
    #define BFRW(nf, kt) (*(const bf16x8*)(Bf + (size_t)((nf) * 16 + (kt)) * 512))

    GLOAD_LDS16(Ap, &As[0][wo]); Ap += 32;
    #pragma unroll
    for (int nf = 0; nf < 4; ++nf) bfr[0][nf] = BFRW(nf, 0);
    PROLOGUE_FENCE();

    #pragma unroll
    for (int kt = 0; kt < 16; ++kt) {
        const int cur3 = kt % 3, nxt3 = (kt + 1) % 3;
        const int cur2 = kt & 1;
        if (kt < 15) {
            GLOAD_LDS16(Ap, &As[nxt3][wo]); Ap += 32;
            #pragma unroll
            for (int nf = 0; nf < 4; ++nf) bfr[cur2 ^ 1][nf] = BFRW(nf, kt + 1);
            if (kt == 0) asm volatile("s_waitcnt vmcnt(0)" ::: "memory");
            else         asm volatile("s_waitcnt vmcnt(5)" ::: "memory");
        } else {
            asm volatile("s_waitcnt vmcnt(0)" ::: "memory");
        }
        BARRIER_FENCED();

        const bf16x8 af = *(const bf16x8*)&As[cur3][(w * 16 + u) * 32 + k0];
        __builtin_amdgcn_s_setprio(1);
        #pragma unroll
        for (int nf = 0; nf < 4; ++nf)
            acc[nf] = __builtin_amdgcn_mfma_f32_16x16x32_bf16(
                af, bfr[cur2][nf], acc[nf], 0, 0, 0);
        __builtin_amdgcn_s_setprio(0);
    }

    #pragma unroll
    for (int r = 0; r < 4; ++r) {
        const int row = m0 + w * 16 + (q << 2) + r;
        float l[4];
        #pragma unroll
        for (int nf = 0; nf < 4; ++nf) l[nf] = acc[nf][r] + bout[nf * 16 + u];

        float mv = l[0]; int mi = u;
        #pragma unroll
        for (int nf = 1; nf < 4; ++nf)
            if (l[nf] > mv) { mv = l[nf]; mi = nf * 16 + u; }
        #pragma unroll
        for (int off = 1; off <= 8; off <<= 1) {
            const float ov = __shfl_xor(mv, off, 64);
            const int   oi = __shfl_xor(mi, off, 64);
            if (ov > mv || (ov == mv && oi < mi)) { mv = ov; mi = oi; }
        }
        float se = 0.f;
        #pragma unroll
        for (int nf = 0; nf < 4; ++nf) se += __expf(l[nf] - mv);
        #pragma unroll
        for (int off = 1; off <= 8; off <<= 1) se += __shfl_xor(se, off, 64);
        const float lse = logf(se);

        #pragma unroll
        for (int nf = 0; nf < 4; ++nf)
            y[(size_t)row * ATOM + nf * 16 + u] = l[nf] - mv - lse;
        if (u == 0) p[row] = mi;
    }
}

// ---------------------------------------------------------------------------
// Init GEMM (enc -> h): 128x128 tile, LDS-staged, tanh epilogue split h0|h1.
// ---------------------------------------------------------------------------
__global__ __launch_bounds__(256) void gemm_init(
    const __bf16* __restrict__ A, const __bf16* __restrict__ B,
    int N, int K, const float* __restrict__ bias,
    float* __restrict__ H0f, __bf16* __restrict__ H0b,
    float* __restrict__ H1f, __bf16* __restrict__ H1b)
{
    __shared__ __bf16 As[128 * 32];
    __shared__ __bf16 Bs[128 * 32];

    const int tid  = threadIdx.x;
    const int lane = tid & 63;
    const int w    = tid >> 6;
    const int wm   = w >> 1, wn = w & 1;
    const int m0   = blockIdx.x * 128;
    const int n0   = blockIdx.y * 128;

    f32x4 acc[4][4] = {};

    const int i0 = w * 64 + lane;
    const int i1 = i0 + 256;
    const __bf16* Ap0 = A + (size_t)(m0 + (i0 >> 2)) * K + (i0 & 3) * 8;
    const __bf16* Ap1 = A + (size_t)(m0 + (i1 >> 2)) * K + (i1 & 3) * 8;
    const __bf16* Bp0 = B + (size_t)(n0 + (i0 >> 2)) * K + (i0 & 3) * 8;
    const __bf16* Bp1 = B + (size_t)(n0 + (i1 >> 2)) * K + (i1 & 3) * 8;
    __bf16* As0 = As + w * 512;
    __bf16* As1 = As + 2048 + w * 512;
    __bf16* Bs0 = Bs + w * 512;
    __bf16* Bs1 = Bs + 2048 + w * 512;

    const int mrow = wm * 64 + (lane & 15);
    const int nrow = wn * 64 + (lane & 15);
    const int koff = (lane >> 4) * 8;

    for (int kt = 0; kt < K / 32; ++kt) {
        __syncthreads();
        GLOAD_LDS16(Ap0, As0);
        GLOAD_LDS16(Ap1, As1);
        GLOAD_LDS16(Bp0, Bs0);
        GLOAD_LDS16(Bp1, Bs1);
        Ap0 += 32; Ap1 += 32; Bp0 += 32; Bp1 += 32;
        __syncthreads();

        bf16x8 af[4], bfr[4];
        #pragma unroll
        for (int f = 0; f < 4; ++f) {
            af[f]  = *(const bf16x8*)&As[(mrow + f * 16) * 32 + koff];
            bfr[f] = *(const bf16x8*)&Bs[(nrow + f * 16) * 32 + koff];
        }
        #pragma unroll
        for (int mf = 0; mf < 4; ++mf)
            #pragma unroll
            for (int nf = 0; nf < 4; ++nf)
                acc[mf][nf] = __builtin_amdgcn_mfma_f32_16x16x32_bf16(
                    af[mf], bfr[nf], acc[mf][nf], 0, 0, 0);
    }

    const int colb = n0 + wn * 64 + (lane & 15);
    const int rowb = m0 + wm * 64 + ((lane >> 4) << 2);
    #pragma unroll
    for (int mf = 0; mf < 4; ++mf)
        #pragma unroll
        for (int nf = 0; nf < 4; ++nf) {
            const int col = colb + nf * 16;
            #pragma unroll
            for (int r = 0; r < 4; ++r) {
                const int row = rowb + mf * 16 + r;
                const float v = tanhf(acc[mf][nf][r] + bias[col]);
                if (col < HID) {
                    H0f[(size_t)row * HID + col] = v;
                    H0b[(size_t)row * HID + col] = (__bf16)v;
                } else {
                    H1f[(size_t)row * HID + col - HID] = v;
                    H1b[(size_t)row * HID + col - HID] = (__bf16)v;
                }
            }
        }
}

// ---------------------------------------------------------------------------
// prep kernels
// ---------------------------------------------------------------------------
__device__ inline int permQ(int q) {          // permuted q -> original row
    const int t = q / 48, rem = q % 48;
    return (rem / 16) * HID + t * 16 + (rem % 16);
}

// frag-layout offset for elem (r, k) of a [R][512] matrix
__device__ inline size_t fragOff(int r, int k) {
    return (size_t)((r >> 4) * 16 + (k >> 5)) * 512 +
           ((k >> 3) & 3) * 128 + (r & 15) * 8 + (k & 7);
}

__global__ __launch_bounds__(256) void f2b(const float* __restrict__ s,
                                           __bf16* __restrict__ d, int n)
{
    const int i = (blockIdx.x * 256 + threadIdx.x) * 4;
    if (i + 3 < n) {
        const float4 v = *(const float4*)(s + i);
        bf16x4 o = { (__bf16)v.x, (__bf16)v.y, (__bf16)v.z, (__bf16)v.w };
        *(bf16x4*)(d + i) = o;
    }
}

// gate-perm + frag layout for the three 1536x512 GRU weights
__global__ __launch_bounds__(256) void f2bpf(const float* __restrict__ s,
                                             __bf16* __restrict__ d)
{
    const int idx = blockIdx.x * 256 + threadIdx.x;   // 1536*128
    const int q = idx >> 7, k4 = (idx & 127) << 2;
    const int o = permQ(q);
    const float4 v = *(const float4*)(s + (size_t)o * HID + k4);
    bf16x4 ov = { (__bf16)v.x, (__bf16)v.y, (__bf16)v.z, (__bf16)v.w };
    *(bf16x4*)(d + fragOff(q, k4)) = ov;
}

// frag layout for wout (64 x 512)
__global__ __launch_bounds__(256) void f2bf(const float* __restrict__ s,
                                            __bf16* __restrict__ d)
{
    const int idx = blockIdx.x * 256 + threadIdx.x;   // 64*128
    if (idx >= ATOM * 128) return;
    const int r = idx >> 7, k4 = (idx & 127) << 2;
    const float4 v = *(const float4*)(s + (size_t)r * HID + k4);
    bf16x4 ov = { (__bf16)v.x, (__bf16)v.y, (__bf16)v.z, (__bf16)v.w };
    *(bf16x4*)(d + fragOff(r, k4)) = ov;
}

__global__ __launch_bounds__(256) void bperm(const float* __restrict__ s,
                                             float* __restrict__ d)
{
    const int q = blockIdx.x * 256 + threadIdx.x;
    if (q < GATE3) d[q] = s[permQ(q)];
}

__global__ __launch_bounds__(256) void g0pk(const float* __restrict__ emb,
                                            const float* __restrict__ wih0,
                                            const float* __restrict__ bih0,
                                            float* __restrict__ G0p)
{
    const int i = blockIdx.x * 256 + threadIdx.x;   // 64*1536
    if (i >= ATOM * GATE3) return;
    const int a = i / GATE3, q = i % GATE3;
    const int o = permQ(q);
    float s = bih0[o];
    for (int k = 0; k < 50; ++k) s += emb[a * 50 + k] * wih0[o * 50 + k];
    G0p[i] = s;
}

__global__ __launch_bounds__(256) void initp(int* __restrict__ p)
{
    const int i = blockIdx.x * 256 + threadIdx.x;
    if (i < B_ROWS) p[i] = 1;   // SOS
}

// ---------------------------------------------------------------------------
extern "C" void kernel_launch(void* const* d_in, const int* in_sizes, int n_in,
                              void* d_out, int out_size, void* d_ws, size_t ws_size,
                              hipStream_t stream)
{
    (void)in_sizes; (void)n_in; (void)out_size; (void)ws_size;
    const float* enc   = (const float*)d_in[0];
    const float* emb   = (const float*)d_in[1];
    const float* w_h0  = (const float*)d_in[2];
    const float* b_h0  = (const float*)d_in[3];
    const float* w_ih0 = (const float*)d_in[4];
    const float* w_hh0 = (const float*)d_in[5];
    const float* b_ih0 = (const float*)d_in[6];
    const float* b_hh0 = (const float*)d_in[7];
    const float* w_ih1 = (const float*)d_in[8];
    const float* w_hh1 = (const float*)d_in[9];
    const float* b_ih1 = (const float*)d_in[10];
    const float* b_hh1 = (const float*)d_in[11];
    const float* w_out = (const float*)d_in[12];
    const float* b_out = (const float*)d_in[13];
    float* out = (float*)d_out;

    char* ws = (char*)d_ws;
    size_t off = 0;
    auto alloc = [&](size_t bytes) -> void* {
        void* pp = ws + off;
        off = (off + bytes + 255) & ~(size_t)255;
        return pp;
    };
    __bf16* whh0f = (__bf16*)alloc((size_t)GATE3 * HID * 2);
    __bf16* wih1f = (__bf16*)alloc((size_t)GATE3 * HID * 2);
    __bf16* whh1f = (__bf16*)alloc((size_t)GATE3 * HID * 2);
    __bf16* woutf = (__bf16*)alloc((size_t)ATOM * HID * 2);
    float*  G0p   = (float*) alloc((size_t)ATOM * GATE3 * 4);
    float*  bhh0p = (float*) alloc(GATE3 * 4);
    float*  bih1p = (float*) alloc(GATE3 * 4);
    float*  bhh1p = (float*) alloc(GATE3 * 4);
    float*  h0f[2]; __bf16* h0b[2]; float* h1f[2]; __bf16* h1b[2];
    for (int i = 0; i < 2; ++i) {
        h0f[i] = (float*) alloc((size_t)B_ROWS * HID * 4);
        h0b[i] = (__bf16*)alloc((size_t)B_ROWS * HID * 2);
        h1f[i] = (float*) alloc((size_t)B_ROWS * HID * 4);
        h1b[i] = (__bf16*)alloc((size_t)B_ROWS * HID * 2);
    }
    int* p = (int*)alloc((size_t)B_ROWS * 4);
    __bf16* enc_b = (__bf16*)alloc((size_t)B_ROWS * 1024 * 2);
    __bf16* wh0b  = (__bf16*)alloc((size_t)1024 * 1024 * 2);

    // ---- prep ----
    f2b  <<<8192, 256, 0, stream>>>(enc,  enc_b, B_ROWS * 1024);
    f2b  <<<1024, 256, 0, stream>>>(w_h0, wh0b,  1024 * 1024);
    f2bf <<<32,   256, 0, stream>>>(w_out, woutf);
    f2bpf<<<768,  256, 0, stream>>>(w_hh0, whh0f);
    f2bpf<<<768,  256, 0, stream>>>(w_ih1, wih1f);
    f2bpf<<<768,  256, 0, stream>>>(w_hh1, whh1f);
    bperm<<<6, 256, 0, stream>>>(b_hh0, bhh0p);
    bperm<<<6, 256, 0, stream>>>(b_ih1, bih1p);
    bperm<<<6, 256, 0, stream>>>(b_hh1, bhh1p);
    g0pk<<<384, 256, 0, stream>>>(emb, w_ih0, b_ih0, G0p);
    initp<<<32, 256, 0, stream>>>(p);

    gemm_init<<<dim3(B_ROWS / 128, 1024 / 128), 256, 0, stream>>>(
        enc_b, wh0b, 1024, 1024, b_h0, h0f[0], h0b[0], h1f[0], h1b[0]);

    // ---- 49 decode steps: 3 launches each ----
    const dim3 gGrid(B_ROWS / 128, GATE3 / 192);   // m-tile fastest (XCD locality)
    for (int step = 0; step < NSTEP; ++step) {
        const int cur = step & 1, nxt = cur ^ 1;
        gru0_step<<<gGrid, 256, 0, stream>>>(
            h0b[cur], whh0f, G0p, p, bhh0p, h0f[cur], h0f[nxt], h0b[nxt]);
        gru1_fused<<<gGrid, 256, 0, stream>>>(
            h0b[nxt], wih1f, h1b[cur], whh1f, bih1p, bhh1p,
            h1f[cur], h1f[nxt], h1b[nxt]);
        out_mfma<<<B_ROWS / 32, 128, 0, stream>>>(
            h1b[nxt], woutf, b_out, out + (size_t)step * B_ROWS * ATOM, p);
    }
}

// Round 9
// 3512.431 us; speedup vs baseline: 2.4241x; 1.5512x over previous
//
#include <hip/hip_runtime.h>
#include <hip/hip_bf16.h>
#include <cstdint>
#include <cstddef>

// ---------------------------------------------------------------------------
// 2-layer GRU decoder. B=8192, H=512, ENC=1024, ATOM=64, 49 steps.
// 3 kernels/step: gru0_step, gru1_fused, out_mfma.
// Gate-permuted weights: q = 48*(j/16) + 16*g + (j%16) <-> orig row g*512+j.
// Grid dim3(128,8): m-tile fastest-varying => XCD L2 locality on weights.
// R9: DEPTH-3 pipeline. R8 showed the kernels sit at ~1 TB/s = Little's-law
//     ceiling (12 waves/CU x 8KB in-flight / ~900cyc HBM). Fix: 4 LDS bufs +
//     4-slot B-reg ring, 3 groups in flight (issue g(kt+3) AFTER barrier kt;
//     steady wait vmcnt(2G), tail G, 0). WAR safe by the R6 invariant
//     (ds_reads consumed by MFMA before next barrier; writes issued after
//     the barrier). Iter-0 full drain (R3 lesson), refills by iter 3.
//     gru1 = K=1024 concat loop (R8's r/z-sum trick, M=64): acc 96->64 VGPR
//     making room for the B-ring; n-gate parts kept split (ani/anh).
//     M=64, grid (128,8) restored (R8's M=128 halved the grid -> occ 10%).
// Frag layout for a [R][512] bf16 matrix read as MFMA A/B operand:
//     elem(r,k) -> ((r>>4)*16 + (k>>5))*512 + ((k>>3)&3)*128 + (r&15)*8 + (k&7)
//     => frag (fr,kt) is a contiguous 1KB block, lane l reads l*16B.
// ---------------------------------------------------------------------------

typedef __attribute__((ext_vector_type(8))) __bf16 bf16x8;
typedef __attribute__((ext_vector_type(4))) __bf16 bf16x4;
typedef __attribute__((ext_vector_type(4))) float f32x4;

#define B_ROWS 8192
#define HID 512
#define GATE3 1536
#define ATOM 64
#define NSTEP 49

#define GLOAD_LDS16(gp, sp)                                                   \
  __builtin_amdgcn_global_load_lds(                                           \
      (__attribute__((address_space(1))) void*)(gp),                          \
      (__attribute__((address_space(3))) void*)(sp), 16, 0, 0)

#define PROLOGUE_FENCE()                                                      \
  do {                                                                        \
    __builtin_amdgcn_sched_barrier(0);                                        \
    asm volatile("" ::: "memory");                                            \
  } while (0)

#define BARRIER_FENCED()                                                      \
  do {                                                                        \
    __builtin_amdgcn_s_barrier();                                             \
    asm volatile("" ::: "memory");                                            \
    __builtin_amdgcn_sched_barrier(0);                                        \
  } while (0)

__device__ inline float sig_(float x) { return 1.f / (1.f + __expf(-x)); }
__device__ inline float tanh_(float x) { return 2.f / (1.f + __expf(-2.f * x)) - 1.f; }

// ---------------------------------------------------------------------------
// K1: GRU0. gh0 = h0 @ whh0f^T; gi0 = G0p[p[row]] (b_ih0 folded);
// gate update -> h0_new (fp32 + bf16 mirror). M=64, 4 waves.
// A: LDS 4-buf (16KB) + swizzle. B: 4-slot reg ring. Group G=4 (1 stage +
// 3 B-loads); depth 3: steady vmcnt(8), tail vmcnt(4)/vmcnt(0).
// ---------------------------------------------------------------------------
__global__ __launch_bounds__(256) void gru0_step(
    const __bf16* __restrict__ h0b_c, const __bf16* __restrict__ whh0f,
    const float* __restrict__ G0p, const int* __restrict__ p,
    const float* __restrict__ bhh0p,
    const float* __restrict__ h0f_c, float* __restrict__ h0f_n,
    __bf16* __restrict__ h0b_n)
{
    __shared__ __bf16 As[4][64 * 32];    // 4 x 4 KB

    const int tid = threadIdx.x, lane = tid & 63, w = tid >> 6;
    const int u = lane & 15, q = lane >> 4;
    const int m0 = blockIdx.x * 64;
    const int t_ = blockIdx.y * 4 + w;
    const int j  = t_ * 16 + u;
    const int qb = t_ * 48 + u;
    const int k0   = (q ^ ((u >> 1) & 3)) * 8;              // A read col
    const int scol = ((tid & 3) ^ ((tid >> 3) & 3)) * 8;    // A stage col
    const int wo = w * 512;

    const __bf16* Ap = h0b_c + (size_t)(m0 + (tid >> 2)) * HID + scol;
    const __bf16* Bf = whh0f + (size_t)(t_ * 48) * 512 + lane * 8;
    #define BFR0(g, kt) (*(const bf16x8*)(Bf + (size_t)((g) * 16 + (kt)) * 512))

    f32x4 acc[4][3] = {};
    bf16x8 bfr[4][3];

    // prologue: groups 0,1,2 (fenced so issue order = program order)
    #pragma unroll
    for (int pg = 0; pg < 3; ++pg) {
        GLOAD_LDS16(Ap, &As[pg][wo]); Ap += 32;
        bfr[pg][0] = BFR0(0, pg);
        bfr[pg][1] = BFR0(1, pg);
        bfr[pg][2] = BFR0(2, pg);
        PROLOGUE_FENCE();
    }

    #pragma unroll
    for (int kt = 0; kt < 16; ++kt) {
        if (kt == 0)       asm volatile("s_waitcnt vmcnt(0)" ::: "memory");
        else if (kt <= 13) asm volatile("s_waitcnt vmcnt(8)" ::: "memory");
        else if (kt == 14) asm volatile("s_waitcnt vmcnt(4)" ::: "memory");
        else               asm volatile("s_waitcnt vmcnt(0)" ::: "memory");
        BARRIER_FENCED();                    // As[kt&3] ready for all waves

        if (kt + 3 < 16) {                   // issue g(kt+3) AFTER barrier
            const int s = (kt + 3) & 3;
            GLOAD_LDS16(Ap, &As[s][wo]); Ap += 32;
            bfr[s][0] = BFR0(0, kt + 3);
            bfr[s][1] = BFR0(1, kt + 3);
            bfr[s][2] = BFR0(2, kt + 3);
            PROLOGUE_FENCE();
        }

        bf16x8 af[4];
        #pragma unroll
        for (int mf = 0; mf < 4; ++mf)
            af[mf] = *(const bf16x8*)&As[kt & 3][(mf * 16 + u) * 32 + k0];
        __builtin_amdgcn_s_setprio(1);
        #pragma unroll
        for (int mf = 0; mf < 4; ++mf)
            #pragma unroll
            for (int g = 0; g < 3; ++g)
                acc[mf][g] = __builtin_amdgcn_mfma_f32_16x16x32_bf16(
                    af[mf], bfr[kt & 3][g], acc[mf][g], 0, 0, 0);
        __builtin_amdgcn_s_setprio(0);
    }

    const float bhr = bhh0p[qb], bhz = bhh0p[qb + 16], bhn = bhh0p[qb + 32];
    const int rbase = m0 + (q << 2);
    #pragma unroll
    for (int mf = 0; mf < 4; ++mf)
        #pragma unroll
        for (int r = 0; r < 4; ++r) {
            const int row = rbase + mf * 16 + r;
            const float* g0 = G0p + (size_t)p[row] * GATE3 + qb;
            const float rr = sig_(g0[0]  + acc[mf][0][r] + bhr);
            const float zz = sig_(g0[16] + acc[mf][1][r] + bhz);
            const float nn = tanh_(g0[32] + rr * (acc[mf][2][r] + bhn));
            const float hp = h0f_c[(size_t)row * HID + j];
            const float hv = (1.f - zz) * nn + zz * hp;
            h0f_n[(size_t)row * HID + j] = hv;
            h0b_n[(size_t)row * HID + j] = (__bf16)hv;
        }
}

// ---------------------------------------------------------------------------
// K2: GRU1, K=1024 concat loop (32 iters): phase 0 (t<16) A=h0_new, B=wih1;
// phase 1 (t>=16) A=h1, B=whh1. r,z accumulate across both phases (gates are
// sums); n parts split (ani/anh). M=64, 4 waves; acc 64 VGPR.
// A: LDS 4-buf (16KB). B: 4-slot reg ring. G=4; depth 3: vmcnt(8)/4/0.
// ---------------------------------------------------------------------------
__global__ __launch_bounds__(256) void gru1_fused(
    const __bf16* __restrict__ h0b_n, const __bf16* __restrict__ wih1f,
    const __bf16* __restrict__ h1b_c, const __bf16* __restrict__ whh1f,
    const float* __restrict__ bih1p, const float* __restrict__ bhh1p,
    const float* __restrict__ h1f_c, float* __restrict__ h1f_n,
    __bf16* __restrict__ h1b_n)
{
    __shared__ __bf16 As[4][64 * 32];    // 4 x 4 KB (one A stream, K-concat)

    const int tid = threadIdx.x, lane = tid & 63, w = tid >> 6;
    const int u = lane & 15, q = lane >> 4;
    const int m0 = blockIdx.x * 64;
    const int t_ = blockIdx.y * 4 + w;
    const int j  = t_ * 16 + u;
    const int qb = t_ * 48 + u;
    const int k0   = (q ^ ((u >> 1) & 3)) * 8;
    const int scol = ((tid & 3) ^ ((tid >> 3) & 3)) * 8;
    const int wo = w * 512;

    const __bf16* Ai = h0b_n + (size_t)(m0 + (tid >> 2)) * HID + scol;
    const __bf16* Ah = h1b_c + (size_t)(m0 + (tid >> 2)) * HID + scol;
    const __bf16* Bi = wih1f + (size_t)(t_ * 48) * 512 + lane * 8;
    const __bf16* Bh = whh1f + (size_t)(t_ * 48) * 512 + lane * 8;

    f32x4 arz[4][2] = {};   // r,z accumulated over K=1024 (both phases)
    f32x4 ani[4] = {};      // n input part  (phase 0)
    f32x4 anh[4] = {};      // n hidden part (phase 1)
    bf16x8 bfr[4][3];

    // prologue: tiles 0,1,2 (phase 0)
    #pragma unroll
    for (int pg = 0; pg < 3; ++pg) {
        GLOAD_LDS16(Ai + (size_t)pg * 32, &As[pg][wo]);
        bfr[pg][0] = *(const bf16x8*)(Bi + (size_t)(0 * 16 + pg) * 512);
        bfr[pg][1] = *(const bf16x8*)(Bi + (size_t)(1 * 16 + pg) * 512);
        bfr[pg][2] = *(const bf16x8*)(Bi + (size_t)(2 * 16 + pg) * 512);
        PROLOGUE_FENCE();
    }

    #pragma unroll
    for (int kt = 0; kt < 32; ++kt) {
        if (kt == 0)       asm volatile("s_waitcnt vmcnt(0)" ::: "memory");
        else if (kt <= 29) asm volatile("s_waitcnt vmcnt(8)" ::: "memory");
        else if (kt == 30) asm volatile("s_waitcnt vmcnt(4)" ::: "memory");
        else               asm volatile("s_waitcnt vmcnt(0)" ::: "memory");
        BARRIER_FENCED();

        if (kt + 3 < 32) {
            const int t = kt + 3, s = t & 3;
            const __bf16* ap = (t < 16 ? Ai : Ah) + (size_t)(t & 15) * 32;
            const __bf16* bp = (t < 16 ? Bi : Bh);
            GLOAD_LDS16(ap, &As[s][wo]);
            bfr[s][0] = *(const bf16x8*)(bp + (size_t)(0 * 16 + (t & 15)) * 512);
            bfr[s][1] = *(const bf16x8*)(bp + (size_t)(1 * 16 + (t & 15)) * 512);
            bfr[s][2] = *(const bf16x8*)(bp + (size_t)(2 * 16 + (t & 15)) * 512);
            PROLOGUE_FENCE();
        }

        bf16x8 af[4];
        #pragma unroll
        for (int mf = 0; mf < 4; ++mf)
            af[mf] = *(const bf16x8*)&As[kt & 3][(mf * 16 + u) * 32 + k0];
        __builtin_amdgcn_s_setprio(1);
        #pragma unroll
        for (int mf = 0; mf < 4; ++mf) {
            arz[mf][0] = __builtin_amdgcn_mfma_f32_16x16x32_bf16(
                af[mf], bfr[kt & 3][0], arz[mf][0], 0, 0, 0);
            arz[mf][1] = __builtin_amdgcn_mfma_f32_16x16x32_bf16(
                af[mf], bfr[kt & 3][1], arz[mf][1], 0, 0, 0);
            if (kt < 16)
                ani[mf] = __builtin_amdgcn_mfma_f32_16x16x32_bf16(
                    af[mf], bfr[kt & 3][2], ani[mf], 0, 0, 0);
            else
                anh[mf] = __builtin_amdgcn_mfma_f32_16x16x32_bf16(
                    af[mf], bfr[kt & 3][2], anh[mf], 0, 0, 0);
        }
        __builtin_amdgcn_s_setprio(0);
    }

    const float b1r  = bih1p[qb] + bhh1p[qb];
    const float b1z  = bih1p[qb + 16] + bhh1p[qb + 16];
    const float b1in = bih1p[qb + 32];
    const float b1hn = bhh1p[qb + 32];
    const int rbase = m0 + (q << 2);
    #pragma unroll
    for (int mf = 0; mf < 4; ++mf)
        #pragma unroll
        for (int r = 0; r < 4; ++r) {
            const int row = rbase + mf * 16 + r;
            const float rr = sig_(arz[mf][0][r] + b1r);
            const float zz = sig_(arz[mf][1][r] + b1z);
            const float nn = tanh_(ani[mf][r] + b1in + rr * (anh[mf][r] + b1hn));
            const float hp = h1f_c[(size_t)row * HID + j];
            const float hv = (1.f - zz) * nn + zz * hp;
            h1f_n[(size_t)row * HID + j] = hv;
            h1b_n[(size_t)row * HID + j] = (__bf16)hv;
        }
}

// ---------------------------------------------------------------------------
// K3: logits = h1_new @ w_out^T + b_out (BM=32, N=64, K=512); log_softmax +
// argmax fused. 256 blocks x 128 threads. A: LDS 4-buf; B: 4-slot reg ring.
// G=5 (1 stage + 4 B-loads); depth 3: vmcnt(10)/5/0.
// ---------------------------------------------------------------------------
__global__ __launch_bounds__(128) void out_mfma(
    const __bf16* __restrict__ h1b, const __bf16* __restrict__ woutf,
    const float* __restrict__ bout, float* __restrict__ y, int* __restrict__ p)
{
    __shared__ __bf16 As[4][32 * 32];   // 4 x 2 KB

    const int tid  = threadIdx.x;
    const int lane = tid & 63;
    const int w    = tid >> 6;            // 0..1
    const int m0   = blockIdx.x * 32;
    const int u    = lane & 15, q = lane >> 4;
    const int k0   = (q ^ ((u >> 1) & 3)) * 8;
    const int scol = ((tid & 3) ^ ((tid >> 3) & 3)) * 8;
    const int wo   = w * 512;

    f32x4 acc[4] = {};
    bf16x8 bfr[4][4];

    const __bf16* Ap = h1b + (size_t)(m0 + (tid >> 2)) * HID + scol;
    const __bf16* Bf = woutf + lane * 8;
    #define BFRW(nf, kt) (*(const bf16x8*)(Bf + (size_t)((nf) * 16 + (kt)) * 512))

    #pragma unroll
    for (int pg = 0; pg < 3; ++pg) {
        GLOAD_LDS16(Ap, &As[pg][wo]); Ap += 32;
        #pragma unroll
        for (int nf = 0; nf < 4; ++nf) bfr[pg][nf] = BFRW(nf, pg);
        PROLOGUE_FENCE();
    }

    #pragma unroll
    for (int kt = 0; kt < 16; ++kt) {
        if (kt == 0)       asm volatile("s_waitcnt vmcnt(0)" ::: "memory");
        else if (kt <= 13) asm volatile("s_waitcnt vmcnt(10)" ::: "memory");
        else if (kt == 14) asm volatile("s_waitcnt vmcnt(5)" ::: "memory");
        else               asm volatile("s_waitcnt vmcnt(0)" ::: "memory");
        BARRIER_FENCED();

        if (kt + 3 < 16) {
            const int s = (kt + 3) & 3;
            GLOAD_LDS16(Ap, &As[s][wo]); Ap += 32;
            #pragma unroll
            for (int nf = 0; nf < 4; ++nf) bfr[s][nf] = BFRW(nf, kt + 3);
            PROLOGUE_FENCE();
        }

        const bf16x8 af = *(const bf16x8*)&As[kt & 3][(w * 16 + u) * 32 + k0];
        __builtin_amdgcn_s_setprio(1);
        #pragma unroll
        for (int nf = 0; nf < 4; ++nf)
            acc[nf] = __builtin_amdgcn_mfma_f32_16x16x32_bf16(
                af, bfr[kt & 3][nf], acc[nf], 0, 0, 0);
        __builtin_amdgcn_s_setprio(0);
    }

    #pragma unroll
    for (int r = 0; r < 4; ++r) {
        const int row = m0 + w * 16 + (q << 2) + r;
        float l[4];
        #pragma unroll
        for (int nf = 0; nf < 4; ++nf) l[nf] = acc[nf][r] + bout[nf * 16 + u];

        float mv = l[0]; int mi = u;
        #pragma unroll
        for (int nf = 1; nf < 4; ++nf)
            if (l[nf] > mv) { mv = l[nf]; mi = nf * 16 + u; }
        #pragma unroll
        for (int off = 1; off <= 8; off <<= 1) {
            const float ov = __shfl_xor(mv, off, 64);
            const int   oi = __shfl_xor(mi, off, 64);
            if (ov > mv || (ov == mv && oi < mi)) { mv = ov; mi = oi; }
        }
        float se = 0.f;
        #pragma unroll
        for (int nf = 0; nf < 4; ++nf) se += __expf(l[nf] - mv);
        #pragma unroll
        for (int off = 1; off <= 8; off <<= 1) se += __shfl_xor(se, off, 64);
        const float lse = logf(se);

        #pragma unroll
        for (int nf = 0; nf < 4; ++nf)
            y[(size_t)row * ATOM + nf * 16 + u] = l[nf] - mv - lse;
        if (u == 0) p[row] = mi;
    }
}

// ---------------------------------------------------------------------------
// Init GEMM (enc -> h): 128x128 tile, LDS-staged, tanh epilogue split h0|h1.
// Runs once; left in the simple 2-barrier form.
// ---------------------------------------------------------------------------
__global__ __launch_bounds__(256) void gemm_init(
    const __bf16* __restrict__ A, const __bf16* __restrict__ B,
    int N, int K, const float* __restrict__ bias,
    float* __restrict__ H0f, __bf16* __restrict__ H0b,
    float* __restrict__ H1f, __bf16* __restrict__ H1b)
{
    __shared__ __bf16 As[128 * 32];
    __shared__ __bf16 Bs[128 * 32];

    const int tid  = threadIdx.x;
    const int lane = tid & 63;
    const int w    = tid >> 6;
    const int wm   = w >> 1, wn = w & 1;
    const int m0   = blockIdx.x * 128;
    const int n0   = blockIdx.y * 128;

    f32x4 acc[4][4] = {};

    const int i0 = w * 64 + lane;
    const int i1 = i0 + 256;
    const __bf16* Ap0 = A + (size_t)(m0 + (i0 >> 2)) * K + (i0 & 3) * 8;
    const __bf16* Ap1 = A + (size_t)(m0 + (i1 >> 2)) * K + (i1 & 3) * 8;
    const __bf16* Bp0 = B + (size_t)(n0 + (i0 >> 2)) * K + (i0 & 3) * 8;
    const __bf16* Bp1 = B + (size_t)(n0 + (i1 >> 2)) * K + (i1 & 3) * 8;
    __bf16* As0 = As + w * 512;
    __bf16* As1 = As + 2048 + w * 512;
    __bf16* Bs0 = Bs + w * 512;
    __bf16* Bs1 = Bs + 2048 + w * 512;

    const int mrow = wm * 64 + (lane & 15);
    const int nrow = wn * 64 + (lane & 15);
    const int koff = (lane >> 4) * 8;

    for (int kt = 0; kt < K / 32; ++kt) {
        __syncthreads();
        GLOAD_LDS16(Ap0, As0);
        GLOAD_LDS16(Ap1, As1);
        GLOAD_LDS16(Bp0, Bs0);
        GLOAD_LDS16(Bp1, Bs1);
        Ap0 += 32; Ap1 += 32; Bp0 += 32; Bp1 += 32;
        __syncthreads();

        bf16x8 af[4], bfr[4];
        #pragma unroll
        for (int f = 0; f < 4; ++f) {
            af[f]  = *(const bf16x8*)&As[(mrow + f * 16) * 32 + koff];
            bfr[f] = *(const bf16x8*)&Bs[(nrow + f * 16) * 32 + koff];
        }
        #pragma unroll
        for (int mf = 0; mf < 4; ++mf)
            #pragma unroll
            for (int nf = 0; nf < 4; ++nf)
                acc[mf][nf] = __builtin_amdgcn_mfma_f32_16x16x32_bf16(
                    af[mf], bfr[nf], acc[mf][nf], 0, 0, 0);
    }

    const int colb = n0 + wn * 64 + (lane & 15);
    const int rowb = m0 + wm * 64 + ((lane >> 4) << 2);
    #pragma unroll
    for (int mf = 0; mf < 4; ++mf)
        #pragma unroll
        for (int nf = 0; nf < 4; ++nf) {
            const int col = colb + nf * 16;
            #pragma unroll
            for (int r = 0; r < 4; ++r) {
                const int row = rowb + mf * 16 + r;
                const float v = tanhf(acc[mf][nf][r] + bias[col]);
                if (col < HID) {
                    H0f[(size_t)row * HID + col] = v;
                    H0b[(size_t)row * HID + col] = (__bf16)v;
                } else {
                    H1f[(size_t)row * HID + col - HID] = v;
                    H1b[(size_t)row * HID + col - HID] = (__bf16)v;
                }
            }
        }
}

// ---------------------------------------------------------------------------
// prep kernels
// ---------------------------------------------------------------------------
__device__ inline int permQ(int q) {          // permuted q -> original row
    const int t = q / 48, rem = q % 48;
    return (rem / 16) * HID + t * 16 + (rem % 16);
}

// frag-layout offset for elem (r, k) of a [R][512] matrix
__device__ inline size_t fragOff(int r, int k) {
    return (size_t)((r >> 4) * 16 + (k >> 5)) * 512 +
           ((k >> 3) & 3) * 128 + (r & 15) * 8 + (k & 7);
}

__global__ __launch_bounds__(256) void f2b(const float* __restrict__ s,
                                           __bf16* __restrict__ d, int n)
{
    const int i = (blockIdx.x * 256 + threadIdx.x) * 4;
    if (i + 3 < n) {
        const float4 v = *(const float4*)(s + i);
        bf16x4 o = { (__bf16)v.x, (__bf16)v.y, (__bf16)v.z, (__bf16)v.w };
        *(bf16x4*)(d + i) = o;
    }
}

// gate-perm + frag layout for the three 1536x512 GRU weights
__global__ __launch_bounds__(256) void f2bpf(const float* __restrict__ s,
                                             __bf16* __restrict__ d)
{
    const int idx = blockIdx.x * 256 + threadIdx.x;   // 1536*128
    const int q = idx >> 7, k4 = (idx & 127) << 2;
    const int o = permQ(q);
    const float4 v = *(const float4*)(s + (size_t)o * HID + k4);
    bf16x4 ov = { (__bf16)v.x, (__bf16)v.y, (__bf16)v.z, (__bf16)v.w };
    *(bf16x4*)(d + fragOff(q, k4)) = ov;
}

// frag layout for wout (64 x 512)
__global__ __launch_bounds__(256) void f2bf(const float* __restrict__ s,
                                            __bf16* __restrict__ d)
{
    const int idx = blockIdx.x * 256 + threadIdx.x;   // 64*128
    if (idx >= ATOM * 128) return;
    const int r = idx >> 7, k4 = (idx & 127) << 2;
    const float4 v = *(const float4*)(s + (size_t)r * HID + k4);
    bf16x4 ov = { (__bf16)v.x, (__bf16)v.y, (__bf16)v.z, (__bf16)v.w };
    *(bf16x4*)(d + fragOff(r, k4)) = ov;
}

__global__ __launch_bounds__(256) void bperm(const float* __restrict__ s,
                                             float* __restrict__ d)
{
    const int q = blockIdx.x * 256 + threadIdx.x;
    if (q < GATE3) d[q] = s[permQ(q)];
}

__global__ __launch_bounds__(256) void g0pk(const float* __restrict__ emb,
                                            const float* __restrict__ wih0,
                                            const float* __restrict__ bih0,
                                            float* __restrict__ G0p)
{
    const int i = blockIdx.x * 256 + threadIdx.x;   // 64*1536
    if (i >= ATOM * GATE3) return;
    const int a = i / GATE3, q = i % GATE3;
    const int o = permQ(q);
    float s = bih0[o];
    for (int k = 0; k < 50; ++k) s += emb[a * 50 + k] * wih0[o * 50 + k];
    G0p[i] = s;
}

__global__ __launch_bounds__(256) void initp(int* __restrict__ p)
{
    const int i = blockIdx.x * 256 + threadIdx.x;
    if (i < B_ROWS) p[i] = 1;   // SOS
}

// ---------------------------------------------------------------------------
extern "C" void kernel_launch(void* const* d_in, const int* in_sizes, int n_in,
                              void* d_out, int out_size, void* d_ws, size_t ws_size,
                              hipStream_t stream)
{
    (void)in_sizes; (void)n_in; (void)out_size; (void)ws_size;
    const float* enc   = (const float*)d_in[0];
    const float* emb   = (const float*)d_in[1];
    const float* w_h0  = (const float*)d_in[2];
    const float* b_h0  = (const float*)d_in[3];
    const float* w_ih0 = (const float*)d_in[4];
    const float* w_hh0 = (const float*)d_in[5];
    const float* b_ih0 = (const float*)d_in[6];
    const float* b_hh0 = (const float*)d_in[7];
    const float* w_ih1 = (const float*)d_in[8];
    const float* w_hh1 = (const float*)d_in[9];
    const float* b_ih1 = (const float*)d_in[10];
    const float* b_hh1 = (const float*)d_in[11];
    const float* w_out = (const float*)d_in[12];
    const float* b_out = (const float*)d_in[13];
    float* out = (float*)d_out;

    char* ws = (char*)d_ws;
    size_t off = 0;
    auto alloc = [&](size_t bytes) -> void* {
        void* pp = ws + off;
        off = (off + bytes + 255) & ~(size_t)255;
        return pp;
    };
    __bf16* whh0f = (__bf16*)alloc((size_t)GATE3 * HID * 2);
    __bf16* wih1f = (__bf16*)alloc((size_t)GATE3 * HID * 2);
    __bf16* whh1f = (__bf16*)alloc((size_t)GATE3 * HID * 2);
    __bf16* woutf = (__bf16*)alloc((size_t)ATOM * HID * 2);
    float*  G0p   = (float*) alloc((size_t)ATOM * GATE3 * 4);
    float*  bhh0p = (float*) alloc(GATE3 * 4);
    float*  bih1p = (float*) alloc(GATE3 * 4);
    float*  bhh1p = (float*) alloc(GATE3 * 4);
    float*  h0f[2]; __bf16* h0b[2]; float* h1f[2]; __bf16* h1b[2];
    for (int i = 0; i < 2; ++i) {
        h0f[i] = (float*) alloc((size_t)B_ROWS * HID * 4);
        h0b[i] = (__bf16*)alloc((size_t)B_ROWS * HID * 2);
        h1f[i] = (float*) alloc((size_t)B_ROWS * HID * 4);
        h1b[i] = (__bf16*)alloc((size_t)B_ROWS * HID * 2);
    }
    int* p = (int*)alloc((size_t)B_ROWS * 4);
    __bf16* enc_b = (__bf16*)alloc((size_t)B_ROWS * 1024 * 2);
    __bf16* wh0b  = (__bf16*)alloc((size_t)1024 * 1024 * 2);

    // ---- prep ----
    f2b  <<<8192, 256, 0, stream>>>(enc,  enc_b, B_ROWS * 1024);
    f2b  <<<1024, 256, 0, stream>>>(w_h0, wh0b,  1024 * 1024);
    f2bf <<<32,   256, 0, stream>>>(w_out, woutf);
    f2bpf<<<768,  256, 0, stream>>>(w_hh0, whh0f);
    f2bpf<<<768,  256, 0, stream>>>(w_ih1, wih1f);
    f2bpf<<<768,  256, 0, stream>>>(w_hh1, whh1f);
    bperm<<<6, 256, 0, stream>>>(b_hh0, bhh0p);
    bperm<<<6, 256, 0, stream>>>(b_ih1, bih1p);
    bperm<<<6, 256, 0, stream>>>(b_hh1, bhh1p);
    g0pk<<<384, 256, 0, stream>>>(emb, w_ih0, b_ih0, G0p);
    initp<<<32, 256, 0, stream>>>(p);

    gemm_init<<<dim3(B_ROWS / 128, 1024 / 128), 256, 0, stream>>>(
        enc_b, wh0b, 1024, 1024, b_h0, h0f[0], h0b[0], h1f[0], h1b[0]);

    // ---- 49 decode steps: 3 launches each ----
    const dim3 gGrid(B_ROWS / 64, GATE3 / 192);   // m-tile fastest (XCD locality)
    for (int step = 0; step < NSTEP; ++step) {
        const int cur = step & 1, nxt = cur ^ 1;
        gru0_step<<<gGrid, 256, 0, stream>>>(
            h0b[cur], whh0f, G0p, p, bhh0p, h0f[cur], h0f[nxt], h0b[nxt]);
        gru1_fused<<<gGrid, 256, 0, stream>>>(
            h0b[nxt], wih1f, h1b[cur], whh1f, bih1p, bhh1p,
            h1f[cur], h1f[nxt], h1b[nxt]);
        out_mfma<<<B_ROWS / 32, 128, 0, stream>>>(
            h1b[nxt], woutf, b_out, out + (size_t)step * B_ROWS * ATOM, p);
    }
}